// Round 4
// baseline (159.509 us; speedup 1.0000x reference)
//
#include <hip/hip_runtime.h>

// Round 10 (= Round 9 resubmit; container infra failure, no counters).
// Single-wave64 workgroups, 8x8 quad tile per wave.
// Rationale (R8 counters): fused kernel is stall-bound, not memory-bound
// (warm-L3 replays with 73 KB fetch run at the same 42.8 us as cold 63.6 MB
// dispatches; VALUBusy 22.7%). The 4-wave barrier-coupled block gave only
// ~3-5 independent streams/CU. One wave64 per workgroup -> ~16 independent
// waves/CU (LDS 8.3 KB/block), each self-staging with no cross-wave coupling.
//
// Staging per wave (one own-wave __syncthreads):
//   sT2/sR2: tri2 tp/rot rows i0-1..i0+7 (9), cols j0-1..j0+7 (9 faces,
//            81 floats -> 21 float4 chunks/row, stride 84 fl). Left halo is
//            MERGED into the row (face row base 9*(Q+gi*m+j0-1) >= 0 always,
//            since Q tri1 faces precede the tri2 block). DMA global_load_lds.
//   sV:      verts rows i0-1..i0+8 (10), cols j0..j0+8 (27 fl -> 7 chunks/row,
//            stride 28 fl). DMA. Left col (j0-1) staged as 30 scalar dwords
//            into sVh (stride 4).
//   sN:      normals rows i0..i0+8, cols j0..j0+8 (81 items, load9+compute,
//            stride 28 fl).
//   t1/r1:   direct per-thread register load9, issued first.
// DMA slot audit: every global_load_lds slot is single-region with a
// prefix lane mask (first active lane = lane 0), LDS dest linear = base+lane*16.
// LDS byte budget: sT2/sR2 189*16=3024B each (exact), sV 70*16=1120B (exact).
//
// Energy collapse (verified absmax==0 rounds 1-8):
//   sum_pq coeff[p][q](Dp.Dq) = 3(|u|^2+|w|^2+u.w) + (|a|^2+|b|^2+a.b),
//   a = n1.(R1-R2), b = n2.(R1-R2), H=1.
// Adjacency (verified): quad q=(i,j), f1=tri1=i*m+j, tri2=Q+i*m+j.
//   diag : f2=tri2(i,j):   u=t1r2-t2r2, w=t1r1-t2r0; n1=N[v01], n2=N[v10]
//   horiz: f2=tri2(i-1,j): u=t1r0-t2r0, w=t1r2-t2r1; n1=N[v00], n2=N[v01]
//   vert : f2=tri2(i,j-1): u=t1r0-t2r2, w=t1r1-t2r1; n1=N[v00], n2=N[v10]
// Clamp-garbage audit:
//   faces row r=0 with i0=0 reads row Q-m.. -> feeds only th/rh at w=0 (i=0,
//     horiz masked by i>0). Row-end overreads feed only j>=m quads (masked).
//   verts: negative base only at vr=0&j0=0 (rows r<=1 at i0=0); r=0 feeds only
//     pup at w=0 (i=0, masked); halo dwords clamped to 0 feed only plf at
//     quads with j=0 (vert masked by j>0).
//   col j0-1 face slots feed only tv/rv (masked by j>0 at j0=0).

#define BI 8
#define BJ 8
#define T2ROW 84      // floats per staged face row (21 chunks: 9 faces + pad)
#define VROW  28      // floats per staged vert row (7 chunks: 27 data + 1 pad)
#define NSTRIDE 28    // 9 normals * 3 + 1 pad
#define T2_CH 189     // 9 rows * 21 chunks, per array
#define V_CH  70      // 10 rows * 7 chunks
#define NORM_CNT 81   // 9*9

struct __attribute__((aligned(4))) F4s { float a, b, c, d; };
struct F3 { float x, y, z; };
struct R9 { float v[9]; };

__device__ __forceinline__ R9 load9(const float* __restrict__ p) {
    R9 r;
    F4s u0 = *(const F4s*)p;
    F4s u1 = *(const F4s*)(p + 4);
    r.v[0] = u0.a; r.v[1] = u0.b; r.v[2] = u0.c; r.v[3] = u0.d;
    r.v[4] = u1.a; r.v[5] = u1.b; r.v[6] = u1.c; r.v[7] = u1.d;
    r.v[8] = p[8];
    return r;
}

__device__ __forceinline__ int imin(int a, int b) { return a < b ? a : b; }
__device__ __forceinline__ int imax(int a, int b) { return a > b ? a : b; }

__device__ __forceinline__ void gload_lds16(const float* gp, float* lp) {
    __builtin_amdgcn_global_load_lds(
        (const __attribute__((address_space(1))) void*)gp,
        (__attribute__((address_space(3))) void*)lp, 16, 0, 0);
}

__device__ __forceinline__ F3 normal_of(const R9& r) {
    float e1x = r.v[0] - r.v[3], e1y = r.v[1] - r.v[4], e1z = r.v[2] - r.v[5];
    float e2x = r.v[0] - r.v[6], e2y = r.v[1] - r.v[7], e2z = r.v[2] - r.v[8];
    float nx = e1y * e2z - e1z * e2y;
    float ny = e1z * e2x - e1x * e2z;
    float nz = e1x * e2y - e1y * e2x;
    float inv = 1.0f / sqrtf(nx * nx + ny * ny + nz * nz);
    F3 o; o.x = nx * inv; o.y = ny * inv; o.z = nz * inv; return o;
}

__device__ __forceinline__ float tri_area_p(const float* p, const float* q,
                                            const float* r) {
    float ax = q[0] - p[0], ay = q[1] - p[1], az = q[2] - p[2];
    float bx = r[0] - p[0], by = r[1] - p[1], bz = r[2] - p[2];
    float cx = ay * bz - az * by, cy = az * bx - ax * bz, cz = ax * by - ay * bx;
    return 0.5f * sqrtf(cx * cx + cy * cy + cz * cz);
}

__device__ __forceinline__ float edge_ew(const float* u1, const float* u2,
                                         const float* w1, const float* w2,
                                         const float* rA, const float* rB,
                                         const F3& n1, const F3& n2,
                                         const float* pa, const float* pb,
                                         float asum) {
    float ux = u1[0] - u2[0], uy = u1[1] - u2[1], uz = u1[2] - u2[2];
    float wx = w1[0] - w2[0], wy = w1[1] - w2[1], wz = w1[2] - w2[2];

    float d0 = rA[0] - rB[0], d1 = rA[1] - rB[1], d2 = rA[2] - rB[2];
    float d3 = rA[3] - rB[3], d4 = rA[4] - rB[4], d5 = rA[5] - rB[5];
    float d6 = rA[6] - rB[6], d7 = rA[7] - rB[7], d8 = rA[8] - rB[8];

    float ax = n1.x * d0 + n1.y * d3 + n1.z * d6;
    float ay = n1.x * d1 + n1.y * d4 + n1.z * d7;
    float az = n1.x * d2 + n1.y * d5 + n1.z * d8;
    float bx = n2.x * d0 + n2.y * d3 + n2.z * d6;
    float by = n2.x * d1 + n2.y * d4 + n2.z * d7;
    float bz = n2.x * d2 + n2.y * d5 + n2.z * d8;

    float uu = ux * ux + uy * uy + uz * uz;
    float ww = wx * wx + wy * wy + wz * wz;
    float uw = ux * wx + uy * wy + uz * wz;
    float aa = ax * ax + ay * ay + az * az;
    float bb = bx * bx + by * by + bz * bz;
    float ab = ax * bx + ay * by + az * bz;
    float energy = (3.0f * (uu + ww + uw) + (aa + bb + ab)) * (1.0f / 9.0f);

    float dx = pa[0] - pb[0], dy = pa[1] - pb[1], dz = pa[2] - pb[2];
    return energy * (dx * dx + dy * dy + dz * dz) / asum;
}

__global__ __launch_bounds__(64) void fused_kernel(
        const float* __restrict__ tp,    // (2Q,3,3)
        const float* __restrict__ rot,   // (2Q,3,3)
        const float* __restrict__ verts, // (n*n,3)
        double* __restrict__ partials,
        int n) {
    const int m = n - 1;
    const int Q = m * m;
    const int F = 2 * Q;
    const int V = n * n;
    const int lane = threadIdx.x;    // 0..63
    const int i0 = blockIdx.y * BI;
    const int j0 = blockIdx.x * BJ;
    const int w = lane >> 3;         // quad row in tile, 0..7
    const int l = lane & 7;          // quad col in tile, 0..7
    const int i = i0 + w;
    const int j = j0 + l;

    __shared__ __attribute__((aligned(16))) float sT2[9 * T2ROW];
    __shared__ __attribute__((aligned(16))) float sR2[9 * T2ROW];
    __shared__ __attribute__((aligned(16))) float sV[10 * VROW];
    __shared__ float sVh[10 * 4];
    __shared__ float sN[9 * NSTRIDE];

    // ---- (1) t1/r1 direct register loads, issued first ----
    int f1 = imin(i, m - 1) * m + imin(j, m - 1);
    R9 t1 = load9(tp  + (size_t)9 * f1);
    R9 r1 = load9(rot + (size_t)9 * f1);

    // ---- (2) main staging: direct global->LDS, prefix-masked slots ----
#pragma unroll
    for (int it = 0; it < 8; ++it) {
        if (it < 6) {
            int a = it >= 3;                     // compile-time after unroll
            int ch = (a ? it - 3 : it) * 64 + lane;
            if (ch < T2_CH) {
                int r = ch / 21, c = ch - 21 * r;
                int gi = imin(i0 - 1 + r, m - 1);        // can be -1
                int g = 9 * (Q + gi * m + (j0 - 1)) + 4 * c;  // >= 9*(Q-m-1) >= 0
                g = imin(g, 9 * F - 4);
                gload_lds16((a ? rot : tp) + g,
                            (a ? sR2 : sT2) + ch * 4);
            }
        } else {
            int ch = (it - 6) * 64 + lane;
            if (ch < V_CH) {
                int r = ch / 7, c = ch - 7 * r;
                int vr = imax(imin(i0 - 1 + r, n - 1), 0);
                int g = 3 * (vr * n + j0) + 4 * c;       // >= 0
                g = imin(g, 3 * V - 4);
                gload_lds16(verts + g, sV + ch * 4);
            }
        }
    }

    // ---- (3) verts left-halo scalar loads (col j0-1, 10 rows) ----
    float hval = 0.0f;
    float* hdst = nullptr;
    if (lane < 30) {
        int r = lane / 3, k = lane - 3 * r;
        int vr = imax(imin(i0 - 1 + r, n - 1), 0);
        int g = imax(3 * (vr * n + (j0 - 1)) + k, 0);
        hval = verts[g];
        hdst = sVh + r * 4 + k;
    }

    // ---- (4) normal loads (load9 per item, 81 items) ----
    R9 nraw[2];
    int nofs[2];
#pragma unroll
    for (int it = 0; it < 2; ++it) {
        int s = lane + 64 * it;
        bool act = s < NORM_CNT;
        int sc = act ? s : 0;
        int r = sc / 9, c = sc - 9 * r;
        int gi = imin(i0 + r, n - 1);
        int gj = imin(j0 + c, n - 1);
        nraw[it] = load9(tp + (size_t)9 * (gi * n + gj));
        nofs[it] = act ? (r * NSTRIDE + 3 * c) : -1;
    }

    // ---- (5) LDS stores (halo + normals); main tiles land via DMA ----
    if (hdst) *hdst = hval;
#pragma unroll
    for (int it = 0; it < 2; ++it) {
        if (nofs[it] >= 0) {
            F3 nm = normal_of(nraw[it]);
            sN[nofs[it]] = nm.x; sN[nofs[it] + 1] = nm.y; sN[nofs[it] + 2] = nm.z;
        }
    }

    __syncthreads();   // drains vmcnt(0) (DMA) + lgkmcnt; single-wave barrier

    // ---- (6) compute ----
    double term = 0.0;
    if (i < m && j < m) {
        const float* t2c = sT2 + (w + 1) * T2ROW + 9 * (l + 1);
        const float* r2c = sR2 + (w + 1) * T2ROW + 9 * (l + 1);
        const float* th  = sT2 + w * T2ROW + 9 * (l + 1);
        const float* rh  = sR2 + w * T2ROW + 9 * (l + 1);
        const float* tv  = sT2 + (w + 1) * T2ROW + 9 * l;   // merged halo, no branch
        const float* rv  = sR2 + (w + 1) * T2ROW + 9 * l;

        const float* p00 = sV + (w + 1) * VROW + 3 * l;
        const float* p01 = p00 + 3;
        const float* p10 = sV + (w + 2) * VROW + 3 * l;
        const float* p11 = p10 + 3;
        const float* pup = sV + w * VROW + 3 * (l + 1);
        const float* plf = l ? sV + (w + 2) * VROW + 3 * (l - 1)
                             : sVh + (w + 2) * 4;

        const float* na = sN + w * NSTRIDE + 3 * l;
        const float* nb = na + 3;
        const float* nc = sN + (w + 1) * NSTRIDE + 3 * l;
        F3 nA = { na[0], na[1], na[2] };
        F3 nB = { nb[0], nb[1], nb[2] };
        F3 nC = { nc[0], nc[1], nc[2] };

        float a1   = tri_area_p(p00, p10, p01);
        float a2c  = tri_area_p(p10, p11, p01);
        float a2up = tri_area_p(p00, p01, pup);
        float a2lf = tri_area_p(plf, p10, p00);

        float sum = edge_ew(t1.v + 6, t2c + 6, t1.v + 3, t2c + 0, r1.v, r2c,
                            nB, nC, p01, p10, a1 + a2c);
        float eh = edge_ew(t1.v + 0, th + 0, t1.v + 6, th + 3, r1.v, rh,
                           nA, nB, p00, p01, a1 + a2up);
        float ev = edge_ew(t1.v + 0, tv + 6, t1.v + 3, tv + 3, r1.v, rv,
                           nA, nC, p00, p10, a1 + a2lf);
        sum += (i > 0 ? eh : 0.0f);
        sum += (j > 0 ? ev : 0.0f);
        term = (double)sum;
    }

    // ---- (7) in-wave reduction, one double per workgroup ----
#pragma unroll
    for (int off = 32; off > 0; off >>= 1) term += __shfl_down(term, off, 64);
    if (lane == 0)
        partials[blockIdx.y * gridDim.x + blockIdx.x] = term;
}

__global__ __launch_bounds__(256) void finalize_kernel(
        const double* __restrict__ partials, int P, float* __restrict__ out) {
    double s = 0.0;
    for (int i = threadIdx.x; i < P; i += 256) s += partials[i];
#pragma unroll
    for (int off = 32; off > 0; off >>= 1) s += __shfl_down(s, off, 64);
    __shared__ double sred[4];
    int lane = threadIdx.x & 63, wid = threadIdx.x >> 6;
    if (lane == 0) sred[wid] = s;
    __syncthreads();
    if (threadIdx.x == 0) out[0] = (float)(sred[0] + sred[1] + sred[2] + sred[3]);
}

extern "C" void kernel_launch(void* const* d_in, const int* in_sizes, int n_in,
                              void* d_out, int out_size, void* d_ws, size_t ws_size,
                              hipStream_t stream) {
    const float* tp    = (const float*)d_in[0];
    const float* rot   = (const float*)d_in[1];
    const float* verts = (const float*)d_in[2];

    int V = in_sizes[2] / 3;
    int n = (int)(sqrtf((float)V) + 0.5f);
    int m = n - 1;

    double* partials = (double*)d_ws;
    float*  out      = (float*)d_out;

    dim3 grid((m + BJ - 1) / BJ, (m + BI - 1) / BI);
    int P = grid.x * grid.y;
    fused_kernel<<<grid, 64, 0, stream>>>(tp, rot, verts, partials, n);
    finalize_kernel<<<1, 256, 0, stream>>>(partials, P, out);
}

// Round 5
// 155.892 us; speedup vs baseline: 1.0232x; 1.0232x over previous
//
#include <hip/hip_runtime.h>

// Round 11: 8x16 tile per single wave64 (2 quads/thread: (w,l) and (w,l+8)).
// R8/R10 evidence: kernel is issue/latency-bound, not memory-bound (warm-L3
// replays == cold-HBM time), and extra waves don't help (R10). So: halve
// per-quad staging work, double per-thread ILP, make all LDS reads
// conflict-free, add XCD-chunked block swizzle for L2 locality.
//
// LDS layouts (slot-linear: chunk stride == row stride, DMA dest = base+16*slot):
//   sT2/sR2: 9 rows x 156 fl (39 chunks exactly). Cols j0-1..j0+15 (17 faces,
//            153 fl data + 3 pad). stride 156 == 28 mod 32: reads at
//            9*l' + 156*w' -> no bank collision for per-instruction dl<=7
//            except dw=0 (2-way lanes l/l+32: free).  Left halo MERGED
//            (face row base 9*(Q+gi*m+j0-1) >= 9*(Q-m-1) > 0 always).
//   sV:      10 rows x 52 fl (13 chunks exactly). Cols j0..j0+16 (51 fl + 1
//            pad). stride 52 == 20 mod 32: conflict-free same argument.
//            Left col (j0-1) via separate scalar-clamped sVh (merging into
//            DMA is UNSAFE at vr=0 & j0=0: base 3*(0+j0-1) goes negative and
//            a clamp would shift chunk contents into valid quad (0,0) data).
//   sN:      9 rows x 52 fl: normals rows i0..i0+8, cols j0..j0+16 (load9 of
//            tp at face idx = vertex id gi*n+gj, normal_of, store). 153 items.
// t1/r1 for BOTH quads loaded to registers first.
//
// Energy collapse (verified absmax==0 rounds 1-10):
//   sum_pq coeff[p][q](Dp.Dq) = 3(|u|^2+|w|^2+u.w) + (|a|^2+|b|^2+a.b), H=1.
// Adjacency (verified): quad q=(i,j), f1=tri1=i*m+j, tri2=Q+i*m+j.
//   diag : f2=tri2(i,j):   u=t1r2-t2r2, w=t1r1-t2r0; n1=N[v01], n2=N[v10]
//   horiz: f2=tri2(i-1,j): u=t1r0-t2r0, w=t1r2-t2r1; n1=N[v00], n2=N[v01]
//   vert : f2=tri2(i,j-1): u=t1r0-t2r2, w=t1r1-t2r1; n1=N[v00], n2=N[v10]
// Clamp-garbage audit:
//   faces: row r=0 @ i0=0 reads tri2 row (Q-m..) -> feeds th/rh only at w=0
//     (i=0, horiz masked). col j0-1 slot garbage @ j0=0 feeds tv/rv -> j=0
//     masked. Right-edge 9F-4 clamp shift (gi=m-1 & j0 max) corrupts only
//     col j0+15 = 767 = m -> masked. Row-tail chunk 38 stays inside stride.
//   verts: vr clamps feed only masked rows (r=0 -> pup @ i=0). Chunk c=12
//     covers floats 48..51 = exactly the col-j0+16 slot (+pad): 3V-4 clamp
//     @ vr=n-1 corrupts only that col -> serves p01/p11/pup of j=m quads or
//     pad -> masked. sVh garbage (clamped) feeds plf only at j=0 -> masked.
//   normals: gi/gj clamps at i0+8/j0+16 feed only i=m / j=m quads -> masked.

#define BI 8
#define BJ 16
#define FST 156      // face LDS row stride (floats) = 39 chunks exactly
#define FSLOTS 351   // 9 rows * 39 chunks, per array
#define VST 52       // vert LDS row stride = 13 chunks exactly
#define VSLOTS 130   // 10 rows * 13 chunks
#define NST 52       // normals row stride (floats)
#define NCNT 153     // 9 rows * 17 cols

struct __attribute__((aligned(4))) F4s { float a, b, c, d; };
struct F3 { float x, y, z; };
struct R9 { float v[9]; };

__device__ __forceinline__ R9 load9(const float* __restrict__ p) {
    R9 r;
    F4s u0 = *(const F4s*)p;
    F4s u1 = *(const F4s*)(p + 4);
    r.v[0] = u0.a; r.v[1] = u0.b; r.v[2] = u0.c; r.v[3] = u0.d;
    r.v[4] = u1.a; r.v[5] = u1.b; r.v[6] = u1.c; r.v[7] = u1.d;
    r.v[8] = p[8];
    return r;
}

__device__ __forceinline__ int imin(int a, int b) { return a < b ? a : b; }
__device__ __forceinline__ int imax(int a, int b) { return a > b ? a : b; }

__device__ __forceinline__ void gload_lds16(const float* gp, float* lp) {
    __builtin_amdgcn_global_load_lds(
        (const __attribute__((address_space(1))) void*)gp,
        (__attribute__((address_space(3))) void*)lp, 16, 0, 0);
}

__device__ __forceinline__ F3 normal_of(const R9& r) {
    float e1x = r.v[0] - r.v[3], e1y = r.v[1] - r.v[4], e1z = r.v[2] - r.v[5];
    float e2x = r.v[0] - r.v[6], e2y = r.v[1] - r.v[7], e2z = r.v[2] - r.v[8];
    float nx = e1y * e2z - e1z * e2y;
    float ny = e1z * e2x - e1x * e2z;
    float nz = e1x * e2y - e1y * e2x;
    float inv = 1.0f / sqrtf(nx * nx + ny * ny + nz * nz);
    F3 o; o.x = nx * inv; o.y = ny * inv; o.z = nz * inv; return o;
}

__device__ __forceinline__ float tri_area_p(const float* p, const float* q,
                                            const float* r) {
    float ax = q[0] - p[0], ay = q[1] - p[1], az = q[2] - p[2];
    float bx = r[0] - p[0], by = r[1] - p[1], bz = r[2] - p[2];
    float cx = ay * bz - az * by, cy = az * bx - ax * bz, cz = ax * by - ay * bx;
    return 0.5f * sqrtf(cx * cx + cy * cy + cz * cz);
}

__device__ __forceinline__ float edge_ew(const float* u1, const float* u2,
                                         const float* w1, const float* w2,
                                         const float* rA, const float* rB,
                                         const F3& n1, const F3& n2,
                                         const float* pa, const float* pb,
                                         float asum) {
    float ux = u1[0] - u2[0], uy = u1[1] - u2[1], uz = u1[2] - u2[2];
    float wx = w1[0] - w2[0], wy = w1[1] - w2[1], wz = w1[2] - w2[2];

    float d0 = rA[0] - rB[0], d1 = rA[1] - rB[1], d2 = rA[2] - rB[2];
    float d3 = rA[3] - rB[3], d4 = rA[4] - rB[4], d5 = rA[5] - rB[5];
    float d6 = rA[6] - rB[6], d7 = rA[7] - rB[7], d8 = rA[8] - rB[8];

    float ax = n1.x * d0 + n1.y * d3 + n1.z * d6;
    float ay = n1.x * d1 + n1.y * d4 + n1.z * d7;
    float az = n1.x * d2 + n1.y * d5 + n1.z * d8;
    float bx = n2.x * d0 + n2.y * d3 + n2.z * d6;
    float by = n2.x * d1 + n2.y * d4 + n2.z * d7;
    float bz = n2.x * d2 + n2.y * d5 + n2.z * d8;

    float uu = ux * ux + uy * uy + uz * uz;
    float ww = wx * wx + wy * wy + wz * wz;
    float uw = ux * wx + uy * wy + uz * wz;
    float aa = ax * ax + ay * ay + az * az;
    float bb = bx * bx + by * by + bz * bz;
    float ab = ax * bx + ay * by + az * bz;
    float energy = (3.0f * (uu + ww + uw) + (aa + bb + ab)) * (1.0f / 9.0f);

    float dx = pa[0] - pb[0], dy = pa[1] - pb[1], dz = pa[2] - pb[2];
    return energy * (dx * dx + dy * dy + dz * dz) / asum;
}

__global__ __launch_bounds__(64) void fused_kernel(
        const float* __restrict__ tp,    // (2Q,3,3)
        const float* __restrict__ rot,   // (2Q,3,3)
        const float* __restrict__ verts, // (n*n,3)
        double* __restrict__ partials,
        int n) {
    const int m = n - 1;
    const int Q = m * m;
    const int F = 2 * Q;
    const int V = n * n;
    const int lane = threadIdx.x;    // 0..63

    // XCD-chunked bijective swizzle (nwg % 8 == 0 for n=768; guard otherwise)
    const int gx = gridDim.x;
    const int nb = gx * gridDim.y;
    const int b  = blockIdx.y * gx + blockIdx.x;
    const int b2 = (nb & 7) ? b : ((b & 7) * (nb >> 3) + (b >> 3));
    const int by = b2 / gx;
    const int bx = b2 - by * gx;
    const int i0 = by * BI;
    const int j0 = bx * BJ;

    const int w = lane >> 3;         // quad row in tile, 0..7
    const int l = lane & 7;          // quad col (first of pair), 0..7
    const int i = i0 + w;

    __shared__ __attribute__((aligned(16))) float sT2[9 * FST];
    __shared__ __attribute__((aligned(16))) float sR2[9 * FST];
    __shared__ __attribute__((aligned(16))) float sV[10 * VST];
    __shared__ float sVh[10 * 4];
    __shared__ float sN[9 * NST];

    // ---- (1) t1/r1 for both quads, register loads issued first ----
    int iq  = imin(i, m - 1);
    int f1a = iq * m + imin(j0 + l, m - 1);
    int f1b = iq * m + imin(j0 + l + 8, m - 1);
    R9 t1a = load9(tp  + (size_t)9 * f1a);
    R9 r1a = load9(rot + (size_t)9 * f1a);
    R9 t1b = load9(tp  + (size_t)9 * f1b);
    R9 r1b = load9(rot + (size_t)9 * f1b);

    // ---- (2) face staging: global->LDS DMA, slot-linear dest ----
#pragma unroll
    for (int it = 0; it < 12; ++it) {
        int a = it >= 6;                       // compile-time after unroll
        int ch = (a ? it - 6 : it) * 64 + lane;
        if (ch < FSLOTS) {
            int r = ch / 39, c = ch - 39 * r;
            int gi = imin(i0 - 1 + r, m - 1);  // can be -1
            int g = 9 * (Q + gi * m + (j0 - 1)) + 4 * c;  // >= 9*(Q-m-1) > 0
            g = imin(g, 9 * F - 4);
            gload_lds16((a ? rot : tp) + g, (a ? sR2 : sT2) + ch * 4);
        }
    }
    // ---- (2b) verts staging ----
#pragma unroll
    for (int it = 0; it < 3; ++it) {
        int ch = it * 64 + lane;
        if (ch < VSLOTS) {
            int r = ch / 13, c = ch - 13 * r;
            int vr = imax(imin(i0 - 1 + r, n - 1), 0);
            int g = 3 * (vr * n + j0) + 4 * c;           // >= 0
            g = imin(g, 3 * V - 4);
            gload_lds16(verts + g, sV + ch * 4);
        }
    }

    // ---- (3) verts left-halo scalar loads (col j0-1, 10 rows) ----
    float hval = 0.0f;
    float* hdst = nullptr;
    if (lane < 30) {
        int r = lane / 3, k = lane - 3 * r;
        int vr = imax(imin(i0 - 1 + r, n - 1), 0);
        int g = imax(3 * (vr * n + (j0 - 1)) + k, 0);
        hval = verts[g];
        hdst = sVh + r * 4 + k;
    }

    // ---- (4) normal loads (load9 per item, 153 items) ----
    R9 nraw[3];
    int nofs[3];
#pragma unroll
    for (int it = 0; it < 3; ++it) {
        int s = lane + 64 * it;
        bool act = s < NCNT;
        int sc = act ? s : 0;
        int r = sc / 17, c = sc - 17 * r;
        int gi = imin(i0 + r, n - 1);
        int gj = imin(j0 + c, n - 1);
        nraw[it] = load9(tp + (size_t)9 * (gi * n + gj));
        nofs[it] = act ? (r * NST + 3 * c) : -1;
    }

    // ---- (5) LDS stores (halo + normals); main tiles land via DMA ----
    if (hdst) *hdst = hval;
#pragma unroll
    for (int it = 0; it < 3; ++it) {
        if (nofs[it] >= 0) {
            F3 nm = normal_of(nraw[it]);
            sN[nofs[it]] = nm.x; sN[nofs[it] + 1] = nm.y; sN[nofs[it] + 2] = nm.z;
        }
    }

    __syncthreads();   // single-wave barrier; drains DMA vmcnt + lgkmcnt

    // ---- (6) compute: two independent quads per thread ----
    double term = 0.0;
    if (i < m) {
#pragma unroll
        for (int q = 0; q < 2; ++q) {
            const int lq = l + 8 * q;
            const int jq = j0 + lq;
            if (jq < m) {
                const R9& t1 = q ? t1b : t1a;
                const R9& r1 = q ? r1b : r1a;

                const float* t2c = sT2 + (w + 1) * FST + 9 * (lq + 1);
                const float* r2c = sR2 + (w + 1) * FST + 9 * (lq + 1);
                const float* th  = sT2 + w * FST + 9 * (lq + 1);
                const float* rh  = sR2 + w * FST + 9 * (lq + 1);
                const float* tv  = sT2 + (w + 1) * FST + 9 * lq;
                const float* rv  = sR2 + (w + 1) * FST + 9 * lq;

                const float* p00 = sV + (w + 1) * VST + 3 * lq;
                const float* p01 = p00 + 3;
                const float* p10 = sV + (w + 2) * VST + 3 * lq;
                const float* p11 = p10 + 3;
                const float* pup = sV + w * VST + 3 * (lq + 1);
                const float* plf = lq ? sV + (w + 2) * VST + 3 * (lq - 1)
                                      : sVh + (w + 2) * 4;

                const float* na = sN + w * NST + 3 * lq;
                const float* nb = na + 3;
                const float* nc = sN + (w + 1) * NST + 3 * lq;
                F3 nA = { na[0], na[1], na[2] };
                F3 nB = { nb[0], nb[1], nb[2] };
                F3 nC = { nc[0], nc[1], nc[2] };

                float a1   = tri_area_p(p00, p10, p01);
                float a2c  = tri_area_p(p10, p11, p01);
                float a2up = tri_area_p(p00, p01, pup);
                float a2lf = tri_area_p(plf, p10, p00);

                float sum = edge_ew(t1.v + 6, t2c + 6, t1.v + 3, t2c + 0,
                                    r1.v, r2c, nB, nC, p01, p10, a1 + a2c);
                float eh = edge_ew(t1.v + 0, th + 0, t1.v + 6, th + 3,
                                   r1.v, rh, nA, nB, p00, p01, a1 + a2up);
                float ev = edge_ew(t1.v + 0, tv + 6, t1.v + 3, tv + 3,
                                   r1.v, rv, nA, nC, p00, p10, a1 + a2lf);
                sum += (i > 0 ? eh : 0.0f);
                sum += (jq > 0 ? ev : 0.0f);
                term += (double)sum;
            }
        }
    }

    // ---- (7) in-wave reduction, one double per workgroup ----
#pragma unroll
    for (int off = 32; off > 0; off >>= 1) term += __shfl_down(term, off, 64);
    if (lane == 0)
        partials[blockIdx.y * gridDim.x + blockIdx.x] = term;
}

__global__ __launch_bounds__(256) void finalize_kernel(
        const double* __restrict__ partials, int P, float* __restrict__ out) {
    double s = 0.0;
    for (int i = threadIdx.x; i < P; i += 256) s += partials[i];
#pragma unroll
    for (int off = 32; off > 0; off >>= 1) s += __shfl_down(s, off, 64);
    __shared__ double sred[4];
    int lane = threadIdx.x & 63, wid = threadIdx.x >> 6;
    if (lane == 0) sred[wid] = s;
    __syncthreads();
    if (threadIdx.x == 0) out[0] = (float)(sred[0] + sred[1] + sred[2] + sred[3]);
}

extern "C" void kernel_launch(void* const* d_in, const int* in_sizes, int n_in,
                              void* d_out, int out_size, void* d_ws, size_t ws_size,
                              hipStream_t stream) {
    const float* tp    = (const float*)d_in[0];
    const float* rot   = (const float*)d_in[1];
    const float* verts = (const float*)d_in[2];

    int V = in_sizes[2] / 3;
    int n = (int)(sqrtf((float)V) + 0.5f);
    int m = n - 1;

    double* partials = (double*)d_ws;
    float*  out      = (float*)d_out;

    dim3 grid((m + BJ - 1) / BJ, (m + BI - 1) / BI);
    int P = grid.x * grid.y;
    fused_kernel<<<grid, 64, 0, stream>>>(tp, rot, verts, partials, n);
    finalize_kernel<<<1, 256, 0, stream>>>(partials, P, out);
}

// Round 6
// 147.737 us; speedup vs baseline: 1.0797x; 1.0552x over previous
//
#include <hip/hip_runtime.h>

// Round 12: R8 base (best measured: fused 42.8us, total 145.5) + tri1 tp/rot
// staged via global_load_lds (sT1m/sR1m), replacing the per-thread strided
// load9 of t1/r1. Rationale: R8's cold-vs-warm invariance (63.6MB vs 73KB
// fetch, same 42.8us) says the limiter is transaction/issue throughput on
// divergent strided loads, not bandwidth or latency level. t1/r1 load9 = 6
// stride-36B insts/thread = ~216 cache-line transactions/wave -> replaced by
// coalesced DMA (16B/lane). Normals load9 kept strided this round (LDS cap).
//
// LDS (all main layouts LINEAR for DMA wave-uniform-base + lane*16):
//   sT2m/sR2m: 9 rows x 288 fl (72 ch/row, 648 ch). tri2 rows i0-1..i0+7,
//              cols j0..j0+31.
//   sT1m/sR1m: 8 rows x 288 fl (72 ch/row, 576 ch). tri1 rows i0..i0+7,
//              cols j0..j0+31.
//   sVm:       10 rows x 100 fl (25 ch/row, 250 ch). verts rows i0-1..i0+8.
//   sN:        9x99: vertex-id normals (load9 strided + normal_of).
//   sT2h/sR2h (9x12), sVh (10x4): left-col halos, scalar-staged.
// Wave-slot map (ws = it*4 + wv, 11 iters x 4 waves = 44 slots):
//   0..10 sT2m (guard<648) | 11..21 sR2m | 22..25 sVm (guard<250)
//   26..34 sT1m (576=9*64 exact) | 35..43 sR1m
// Bank audit: strides 288==0 mod 32, reads at 9*l (9 coprime 32) -> per-row
// permutation; lanes l/l+32 are adjacent rows -> 2-way (free, m136).
// sVm stride 100==4 mod 32, reads 3*l -> permutation.
//
// Energy collapse (verified absmax==0 rounds 1-11):
//   sum_pq coeff[p][q](Dp.Dq) = 3(|u|^2+|w|^2+u.w) + (|a|^2+|b|^2+a.b), H=1.
// Adjacency (verified): quad q=(i,j), f1=tri1=i*m+j, tri2=Q+i*m+j.
//   diag : f2=tri2(i,j):   u=t1r2-t2r2, w=t1r1-t2r0; n1=N[v01], n2=N[v10]
//   horiz: f2=tri2(i-1,j): u=t1r0-t2r0, w=t1r2-t2r1; n1=N[v00], n2=N[v01]
//   vert : f2=tri2(i,j-1): u=t1r0-t2r2, w=t1r1-t2r1; n1=N[v00], n2=N[v10]
// Clamp-garbage audit (same consumers as R8, all masked):
//   sT1m row clamp gi=imin(i0+r,m-1) garbage -> only i=m quads (masked).
//   sT1m col wrap at j0+31=767: face id wraps to next tri1 row / tri2 face 0,
//     in-bounds of tp, feeds only j=m quads (masked). 9F-4 clamp for safety.
//   tri2/vert/halo/normal clamps: identical to R8 (verified absmax 0).

#define BI 8
#define BJ 32
#define T2ROW 288     // floats per tri2 row (72 chunks exactly)
#define T1ROW 288     // floats per tri1 row (72 chunks exactly)
#define VROW  100     // floats per vert row (25 chunks; 99 data + 1 pad)
#define NSTRIDE 99    // 33 normals * 3
#define T2_CH 648     // 9 rows * 72
#define T1_CH 576     // 8 rows * 72
#define V_CH  250     // 10 rows * 25
#define NORM_CNT 297  // 9*33
#define HALO_CNT 192  // 2*9*9 face-halo + 10*3 vert-halo dwords

struct __attribute__((aligned(4))) F4s { float a, b, c, d; };
struct F3 { float x, y, z; };
struct R9 { float v[9]; };

__device__ __forceinline__ R9 load9(const float* __restrict__ p) {
    R9 r;
    F4s u0 = *(const F4s*)p;
    F4s u1 = *(const F4s*)(p + 4);
    r.v[0] = u0.a; r.v[1] = u0.b; r.v[2] = u0.c; r.v[3] = u0.d;
    r.v[4] = u1.a; r.v[5] = u1.b; r.v[6] = u1.c; r.v[7] = u1.d;
    r.v[8] = p[8];
    return r;
}

__device__ __forceinline__ int imin(int a, int b) { return a < b ? a : b; }
__device__ __forceinline__ int imax(int a, int b) { return a > b ? a : b; }

__device__ __forceinline__ void gload_lds16(const float* gp, float* lp) {
    __builtin_amdgcn_global_load_lds(
        (const __attribute__((address_space(1))) void*)gp,
        (__attribute__((address_space(3))) void*)lp, 16, 0, 0);
}

__device__ __forceinline__ F3 normal_of(const R9& r) {
    float e1x = r.v[0] - r.v[3], e1y = r.v[1] - r.v[4], e1z = r.v[2] - r.v[5];
    float e2x = r.v[0] - r.v[6], e2y = r.v[1] - r.v[7], e2z = r.v[2] - r.v[8];
    float nx = e1y * e2z - e1z * e2y;
    float ny = e1z * e2x - e1x * e2z;
    float nz = e1x * e2y - e1y * e2x;
    float inv = 1.0f / sqrtf(nx * nx + ny * ny + nz * nz);
    F3 o; o.x = nx * inv; o.y = ny * inv; o.z = nz * inv; return o;
}

__device__ __forceinline__ float tri_area_p(const float* p, const float* q,
                                            const float* r) {
    float ax = q[0] - p[0], ay = q[1] - p[1], az = q[2] - p[2];
    float bx = r[0] - p[0], by = r[1] - p[1], bz = r[2] - p[2];
    float cx = ay * bz - az * by, cy = az * bx - ax * bz, cz = ax * by - ay * bx;
    return 0.5f * sqrtf(cx * cx + cy * cy + cz * cz);
}

__device__ __forceinline__ float edge_ew(const float* u1, const float* u2,
                                         const float* w1, const float* w2,
                                         const float* rA, const float* rB,
                                         const F3& n1, const F3& n2,
                                         const float* pa, const float* pb,
                                         float asum) {
    float ux = u1[0] - u2[0], uy = u1[1] - u2[1], uz = u1[2] - u2[2];
    float wx = w1[0] - w2[0], wy = w1[1] - w2[1], wz = w1[2] - w2[2];

    float d0 = rA[0] - rB[0], d1 = rA[1] - rB[1], d2 = rA[2] - rB[2];
    float d3 = rA[3] - rB[3], d4 = rA[4] - rB[4], d5 = rA[5] - rB[5];
    float d6 = rA[6] - rB[6], d7 = rA[7] - rB[7], d8 = rA[8] - rB[8];

    float ax = n1.x * d0 + n1.y * d3 + n1.z * d6;
    float ay = n1.x * d1 + n1.y * d4 + n1.z * d7;
    float az = n1.x * d2 + n1.y * d5 + n1.z * d8;
    float bx = n2.x * d0 + n2.y * d3 + n2.z * d6;
    float by = n2.x * d1 + n2.y * d4 + n2.z * d7;
    float bz = n2.x * d2 + n2.y * d5 + n2.z * d8;

    float uu = ux * ux + uy * uy + uz * uz;
    float ww = wx * wx + wy * wy + wz * wz;
    float uw = ux * wx + uy * wy + uz * wz;
    float aa = ax * ax + ay * ay + az * az;
    float bb = bx * bx + by * by + bz * bz;
    float ab = ax * bx + ay * by + az * bz;
    float energy = (3.0f * (uu + ww + uw) + (aa + bb + ab)) * (1.0f / 9.0f);

    float dx = pa[0] - pb[0], dy = pa[1] - pb[1], dz = pa[2] - pb[2];
    return energy * (dx * dx + dy * dy + dz * dz) / asum;
}

__global__ __launch_bounds__(256) void fused_kernel(
        const float* __restrict__ tp,    // (2Q,3,3)
        const float* __restrict__ rot,   // (2Q,3,3)
        const float* __restrict__ verts, // (n*n,3)
        double* __restrict__ partials,
        int n) {
    const int m = n - 1;
    const int Q = m * m;
    const int F = 2 * Q;
    const int V = n * n;
    const int tid = threadIdx.x;
    const int i0 = blockIdx.y * BI;
    const int j0 = blockIdx.x * BJ;
    const int w = tid >> 5;          // row within tile, 0..7
    const int l = tid & 31;          // col within tile, 0..31
    const int i = i0 + w;
    const int j = j0 + l;
    const int wv = tid >> 6;         // wave64 id, 0..3
    const int lane = tid & 63;

    __shared__ __attribute__((aligned(16))) float sT2m[9 * T2ROW];
    __shared__ __attribute__((aligned(16))) float sR2m[9 * T2ROW];
    __shared__ __attribute__((aligned(16))) float sT1m[8 * T1ROW];
    __shared__ __attribute__((aligned(16))) float sR1m[8 * T1ROW];
    __shared__ __attribute__((aligned(16))) float sVm[10 * VROW];
    __shared__ float sN[9 * NSTRIDE];
    __shared__ float sT2h[9 * 12];
    __shared__ float sR2h[9 * 12];
    __shared__ float sVh[10 * 4];
    __shared__ double sred[4];

    // ---- (1) main staging: direct global->LDS, wave-slot per region ----
#pragma unroll
    for (int it = 0; it < 11; ++it) {
        int ws = it * 4 + wv;                 // wave-uniform slot id, 0..43
        if (ws < 22) {
            int a = ws >= 11;                 // wave-uniform
            int wl = a ? ws - 11 : ws;
            int chunk = wl * 64 + lane;       // lane-linear
            if (chunk < T2_CH) {
                int r = chunk / 72, c = chunk - r * 72;
                int gi = imin(i0 - 1 + r, m - 1);   // can be -1: face idx >=0
                int g = 9 * (Q + gi * m + j0) + 4 * c;
                g = imin(g, 9 * F - 4);
                gload_lds16((a ? rot : tp) + g,
                            (a ? sR2m : sT2m) + chunk * 4);
            }
        } else if (ws < 26) {
            int chunk = (ws - 22) * 64 + lane;
            if (chunk < V_CH) {
                int r = chunk / 25, c = chunk - r * 25;
                int vr = imax(imin(i0 - 1 + r, n - 1), 0);
                int g = 3 * (vr * n + j0) + 4 * c;
                g = imin(g, 3 * V - 4);
                gload_lds16(verts + g, sVm + chunk * 4);
            }
        } else {
            int a = ws >= 35;                 // wave-uniform
            int wl = a ? ws - 35 : ws - 26;   // 0..8
            int chunk = wl * 64 + lane;       // < 576 exactly
            if (chunk < T1_CH) {
                int r = chunk / 72, c = chunk - r * 72;
                int gi = imin(i0 + r, m - 1);       // tri1 rows i0..i0+7
                int g = 9 * (gi * m + j0) + 4 * c;
                g = imin(g, 9 * F - 4);
                gload_lds16((a ? rot : tp) + g,
                            (a ? sR1m : sT1m) + chunk * 4);
            }
        }
    }

    // ---- (2) halo scalar loads (left column j0-1) ----
    float hval = 0.0f;
    float* hdst = nullptr;
    if (tid < HALO_CNT) {
        if (tid < 162) {
            int a = tid >= 81;
            int t = a ? tid - 81 : tid;
            int r = t / 9, k = t - 9 * r;
            int gi = imin(i0 - 1 + r, m - 1);
            int face = Q + gi * m + (j0 - 1);       // >= Q-m-1 >= 0, < F
            hval = (a ? rot : tp)[9 * face + k];
            hdst = (a ? sR2h : sT2h) + r * 12 + k;
        } else {
            int t = tid - 162;
            int r = t / 3, k = t - 3 * r;
            int vr = imax(imin(i0 - 1 + r, n - 1), 0);
            int g = imax(3 * (vr * n + (j0 - 1)) + k, 0);
            hval = verts[g];
            hdst = sVh + r * 4 + k;
        }
    }

    // ---- (3) normal loads (strided load9, unchanged this round) ----
    R9 nraw[2];
    int nofs[2];
#pragma unroll
    for (int it = 0; it < 2; ++it) {
        int s = tid + 256 * it;
        bool act = s < NORM_CNT;
        int sc = act ? s : 0;
        int r = sc / 33, c = sc - 33 * r;
        int gi = imin(i0 + r, n - 1);
        int gj = imin(j0 + c, n - 1);
        nraw[it] = load9(tp + (size_t)9 * (gi * n + gj));
        nofs[it] = act ? (r * NSTRIDE + 3 * c) : -1;
    }

    // ---- (4) LDS stores (halo + normals); main tiles land via DMA ----
    if (hdst) *hdst = hval;
#pragma unroll
    for (int it = 0; it < 2; ++it) {
        if (nofs[it] >= 0) {
            F3 nm = normal_of(nraw[it]);
            sN[nofs[it]] = nm.x; sN[nofs[it] + 1] = nm.y; sN[nofs[it] + 2] = nm.z;
        }
    }

    __syncthreads();   // drains vmcnt(0) (DMA) + lgkmcnt

    // ---- (5) compute ----
    double term = 0.0;
    if (i < m && j < m) {
        const float* st1 = sT1m + w * T1ROW + 9 * l;
        const float* sr1 = sR1m + w * T1ROW + 9 * l;

        const float* t2c = sT2m + (w + 1) * T2ROW + 9 * l;
        const float* r2c = sR2m + (w + 1) * T2ROW + 9 * l;
        const float* th  = sT2m + w * T2ROW + 9 * l;
        const float* rh  = sR2m + w * T2ROW + 9 * l;
        const float* tv  = l ? sT2m + (w + 1) * T2ROW + 9 * (l - 1)
                             : sT2h + (w + 1) * 12;
        const float* rv  = l ? sR2m + (w + 1) * T2ROW + 9 * (l - 1)
                             : sR2h + (w + 1) * 12;

        const float* p00 = sVm + (w + 1) * VROW + 3 * l;
        const float* p01 = p00 + 3;
        const float* p10 = sVm + (w + 2) * VROW + 3 * l;
        const float* p11 = p10 + 3;
        const float* pup = sVm + w * VROW + 3 * (l + 1);
        const float* plf = l ? sVm + (w + 2) * VROW + 3 * (l - 1)
                             : sVh + (w + 2) * 4;

        const float* na = sN + w * NSTRIDE + 3 * l;
        const float* nb = na + 3;
        const float* nc = sN + (w + 1) * NSTRIDE + 3 * l;
        F3 nA = { na[0], na[1], na[2] };
        F3 nB = { nb[0], nb[1], nb[2] };
        F3 nC = { nc[0], nc[1], nc[2] };

        float a1   = tri_area_p(p00, p10, p01);
        float a2c  = tri_area_p(p10, p11, p01);
        float a2up = tri_area_p(p00, p01, pup);
        float a2lf = tri_area_p(plf, p10, p00);

        float sum = edge_ew(st1 + 6, t2c + 6, st1 + 3, t2c + 0, sr1, r2c,
                            nB, nC, p01, p10, a1 + a2c);
        float eh = edge_ew(st1 + 0, th + 0, st1 + 6, th + 3, sr1, rh,
                           nA, nB, p00, p01, a1 + a2up);
        float ev = edge_ew(st1 + 0, tv + 6, st1 + 3, tv + 3, sr1, rv,
                           nA, nC, p00, p10, a1 + a2lf);
        sum += (i > 0 ? eh : 0.0f);
        sum += (j > 0 ? ev : 0.0f);
        term = (double)sum;
    }

    // ---- (6) block reduction (each wave64 spans 2 tile rows) ----
#pragma unroll
    for (int off = 32; off > 0; off >>= 1) term += __shfl_down(term, off, 64);
    if (lane == 0) sred[wv] = term;
    __syncthreads();
    if (tid == 0)
        partials[blockIdx.y * gridDim.x + blockIdx.x] =
            sred[0] + sred[1] + sred[2] + sred[3];
}

__global__ __launch_bounds__(256) void finalize_kernel(
        const double* __restrict__ partials, int P, float* __restrict__ out) {
    double s = 0.0;
    for (int i = threadIdx.x; i < P; i += 256) s += partials[i];
#pragma unroll
    for (int off = 32; off > 0; off >>= 1) s += __shfl_down(s, off, 64);
    __shared__ double sred[4];
    int lane = threadIdx.x & 63, wid = threadIdx.x >> 6;
    if (lane == 0) sred[wid] = s;
    __syncthreads();
    if (threadIdx.x == 0) out[0] = (float)(sred[0] + sred[1] + sred[2] + sred[3]);
}

extern "C" void kernel_launch(void* const* d_in, const int* in_sizes, int n_in,
                              void* d_out, int out_size, void* d_ws, size_t ws_size,
                              hipStream_t stream) {
    const float* tp    = (const float*)d_in[0];
    const float* rot   = (const float*)d_in[1];
    const float* verts = (const float*)d_in[2];

    int V = in_sizes[2] / 3;
    int n = (int)(sqrtf((float)V) + 0.5f);
    int m = n - 1;

    double* partials = (double*)d_ws;
    float*  out      = (float*)d_out;

    dim3 grid((m + BJ - 1) / BJ, (m + BI - 1) / BI);
    int P = grid.x * grid.y;
    fused_kernel<<<grid, 256, 0, stream>>>(tp, rot, verts, partials, n);
    finalize_kernel<<<1, 256, 0, stream>>>(partials, P, out);
}